// Round 15
// baseline (157.503 us; speedup 1.0000x reference)
//
#include <hip/hip_runtime.h>
#include <hip/hip_bf16.h>
#include <stdint.h>

#define N_ROWS 16384
#define K_DIM  1024
#define N_OUT  4096

typedef __attribute__((ext_vector_type(8))) short short8;
typedef __attribute__((ext_vector_type(4))) float f32x4;
typedef __attribute__((ext_vector_type(4))) __bf16 bf16x4;

// ---------------- prep: block 0 = mask scan, blocks 1..1024 = cvt W -----------
__global__ __launch_bounds__(1024) void prep_kernel(
    const int*   __restrict__ amask,
    const float* __restrict__ W,
    int* __restrict__ idx, int* __restrict__ zidx, int* __restrict__ count,
    __bf16* __restrict__ wb)
{
    const int t = threadIdx.x;
    if (blockIdx.x != 0) {
        const int i = (blockIdx.x - 1) * 1024 + t;   // < 1,048,576 float4
        float4 v = reinterpret_cast<const float4*>(W)[i];
        bf16x4 o;
        o[0] = (__bf16)v.x; o[1] = (__bf16)v.y; o[2] = (__bf16)v.z; o[3] = (__bf16)v.w;
        reinterpret_cast<bf16x4*>(wb)[i] = o;
        return;
    }
    __shared__ int sc[1024];
    const int base = t * 16;
    int mk[16];
#pragma unroll
    for (int g = 0; g < 4; ++g) {
        int4 m4 = reinterpret_cast<const int4*>(amask + base)[g];
        mk[g*4+0] = m4.x; mk[g*4+1] = m4.y; mk[g*4+2] = m4.z; mk[g*4+3] = m4.w;
    }
    int c = 0;
#pragma unroll
    for (int i = 0; i < 16; ++i) c += (mk[i] != 0) ? 1 : 0;
    int v = c;
    sc[t] = v;
    __syncthreads();
    for (int off = 1; off < 1024; off <<= 1) {       // Hillis-Steele scan
        int u = (t >= off) ? sc[t - off] : 0;
        __syncthreads();
        v += u; sc[t] = v;
        __syncthreads();
    }
    int b  = v - c;
    int zb = base - b;
#pragma unroll
    for (int i = 0; i < 16; ++i) {
        int r = base + i;
        if (mk[i] != 0) idx[b++] = r; else zidx[zb++] = r;
    }
    if (t == 1023) count[0] = v;
}

// ---------------- gather: xb[j] = bf16(x[idx[j]]), j < cnt --------------------
__global__ __launch_bounds__(256) void gather_kernel(
    const float* __restrict__ x, const int* __restrict__ idx,
    const int* __restrict__ count, __bf16* __restrict__ xb) {
    const int t = threadIdx.x;                   // 256 threads = 256 float4/row
    const int cnt = count[0];
    for (int j = blockIdx.x; j < cnt; j += 2048) {
        const int row = idx[j];
        float4 v = reinterpret_cast<const float4*>(x + (size_t)row * K_DIM)[t];
        bf16x4 o;
        o[0] = (__bf16)v.x; o[1] = (__bf16)v.y; o[2] = (__bf16)v.z; o[3] = (__bf16)v.w;
        reinterpret_cast<bf16x4*>(xb + (size_t)j * K_DIM)[t] = o;
    }
}

// ------- compacted 128x128 GEMM, T3-minimum double-buffered pipeline ----------
// Identical to R13 except the K-loop: LDS double-buffered (2 x 16KB); per
// K-tile: STAGE(next tile -> buf^1) issued FIRST, then ds_read+MFMA of the
// current buf, then ONE vmcnt(0) + raw s_barrier. Global-load latency hides
// under the MFMA phase instead of being drained before it (the m233-measured
// ~72% stall of the __syncthreads-first structure). Ledger: STAGE targets the
// buffer all waves finished reading one barrier ago; vmcnt(0)-after-MFMA
// guarantees buf^1 is complete before any wave's next-tile ds_read (barrier
// orders it). Zero-fill stays in trivial blocks (after heavy; R13-best).

#define GLL(SRC, DSTOFF)                                                       \
    __builtin_amdgcn_global_load_lds(                                          \
        (const __attribute__((address_space(1))) void*)(SRC),                  \
        (__attribute__((address_space(3))) void*)(ldsc + (DSTOFF)), 16, 0, 0)

// One K-tile. CUR = compile-time buffer index. DO_ST: stage tile KNEXT into
// buf CUR^1. LAST: final tile (no wait/barrier).
#define KTILE(CUR, DO_ST, KNEXT, LAST)                                         \
  {                                                                            \
    if (DO_ST) {                                                               \
      const int kn = (KNEXT) * 32;                                             \
      GLL(pA0 + kn, ((CUR)^1)*16384 + t*16);                                   \
      GLL(pA1 + kn, ((CUR)^1)*16384 + 4096 + t*16);                            \
      GLL(pB0 + kn, ((CUR)^1)*16384 + 8192 + t*16);                            \
      GLL(pB1 + kn, ((CUR)^1)*16384 + 12288 + t*16);                           \
    }                                                                          \
    const short* bse = lds_all + (CUR)*8192;                                   \
    short8 af[4], bf[4];                                                       \
    _Pragma("unroll") for (int mi = 0; mi < 4; ++mi)                           \
      af[mi] = *(const short8*)(bse + (wm*64 + mi*16 + lr)*32 + lk);           \
    _Pragma("unroll") for (int ni = 0; ni < 4; ++ni)                           \
      bf[ni] = *(const short8*)(bse + 4096 + (wn*64 + ni*16 + lr)*32 + lk);    \
    _Pragma("unroll") for (int mi = 0; mi < 4; ++mi)                           \
      _Pragma("unroll") for (int ni = 0; ni < 4; ++ni)                         \
        acc[mi][ni] = __builtin_amdgcn_mfma_f32_16x16x32_bf16(                 \
            af[mi], bf[ni], acc[mi][ni], 0, 0, 0);                             \
    if (!(LAST)) {                                                             \
      asm volatile("s_waitcnt vmcnt(0)" ::: "memory");                         \
      __builtin_amdgcn_s_barrier();                                            \
      asm volatile("" ::: "memory");                                           \
    }                                                                          \
  }

__global__ __launch_bounds__(256) void gemm_kernel(
    const __bf16* __restrict__ A,      // compacted active rows
    const __bf16* __restrict__ B,
    const float*  __restrict__ bias,
    const int*    __restrict__ idx,
    const int*    __restrict__ zidx,
    const int*    __restrict__ count,
    float*        __restrict__ out)
{
    __shared__ short lds_all[16384];   // 32 KB: buf0 @0, buf1 @8192 shorts

    const int cnt = count[0];
    const int aT  = (cnt + 127) >> 7;  // active row-tiles of 128
    const int tn  = blockIdx.x & 31;   // fast axis
    const int tm  = blockIdx.x >> 5;   // 0..127
    const int t   = threadIdx.x;

    if (tm >= aT) {
        // ---- zero-fill role (dispatched after all heavy blocks) ----
        const int ntriv = 4096 - aT * 32;          // >= 1 here
        const int tr    = blockIdx.x - aT * 32;
        const int nz    = N_ROWS - cnt;
        const float4 zf = make_float4(0.f, 0.f, 0.f, 0.f);
        for (int i = tr; i < nz; i += ntriv) {
            const int row = zidx[i];
            float4* p = reinterpret_cast<float4*>(out + (size_t)row * N_OUT);
#pragma unroll
            for (int u = 0; u < 4; ++u)            // 256 thr x 4 float4 = 16 KB
                p[u * 256 + t] = zf;
        }
        return;
    }

    const int l  = t & 63;
    const int w  = t >> 6;             // wave 0..3
    const int wm = w >> 1;             // 0..1
    const int wn = w & 1;              // 0..1

    const int m0 = tm * 128;           // base in COMPACTED row space
    const int n0 = tn * 128;

    // Coalesced staging: thread t stages row (t>>2), k8 = (t&3)*8.
    const int srow = t >> 2;
    const int sk8  = (t & 3) * 8;
    const __bf16* pA0 = A + (size_t)(m0 + srow) * K_DIM + sk8;
    const __bf16* pA1 = pA0 + (size_t)64 * K_DIM;
    const __bf16* pB0 = B + (size_t)(n0 + srow) * K_DIM + sk8;
    const __bf16* pB1 = pB0 + (size_t)64 * K_DIM;
    char* ldsc = (char*)lds_all;

    const int lr = l & 15;
    const int lk = (l >> 4) * 8;

    f32x4 acc[4][4] = {};

    // Prologue: stage tile 0 into buf0; drain; barrier.
    GLL(pA0, t * 16);
    GLL(pA1, 4096 + t * 16);
    GLL(pB0, 8192 + t * 16);
    GLL(pB1, 12288 + t * 16);
    asm volatile("s_waitcnt vmcnt(0)" ::: "memory");
    __builtin_amdgcn_s_barrier();
    asm volatile("" ::: "memory");

#pragma unroll 1
    for (int j = 0; j < 15; ++j) {     // tiles 0..29, staging 1..30
        KTILE(0, 1, 2*j + 1, 0)
        KTILE(1, 1, 2*j + 2, 0)
    }
    KTILE(0, 1, 31, 0)                 // tile 30, stage tile 31
    KTILE(1, 0, 0, 1)                  // tile 31, final

    // Epilogue: bias add, scatter to original rows, guard padded slots.
    const int lq = l >> 4;
    float bv[4];
#pragma unroll
    for (int ni = 0; ni < 4; ++ni) bv[ni] = bias[n0 + wn*64 + ni*16 + lr];

#pragma unroll
    for (int mi = 0; mi < 4; ++mi) {
        const int slot0 = m0 + wm*64 + mi*16 + lq*4;
        int rowid[4]; bool val[4];
#pragma unroll
        for (int r = 0; r < 4; ++r) {
            const int s = slot0 + r;
            val[r] = (s < cnt);
            rowid[r] = val[r] ? idx[s] : 0;
        }
#pragma unroll
        for (int ni = 0; ni < 4; ++ni) {
            const int cc = n0 + wn*64 + ni*16 + lr;
#pragma unroll
            for (int r = 0; r < 4; ++r)
                if (val[r]) out[(size_t)rowid[r] * N_OUT + cc] = acc[mi][ni][r] + bv[ni];
        }
    }
}

// ---------------- naive fp32 fallback (only if ws too small) ------------------
__global__ void naive_kernel(const float* __restrict__ x, const float* __restrict__ W,
                             const float* __restrict__ bias, const int* __restrict__ amask,
                             float* __restrict__ out) {
    int c = blockIdx.x * blockDim.x + threadIdx.x;
    int r = blockIdx.y;
    if (c >= N_OUT) return;
    if (amask[r] == 0) { out[(size_t)r * N_OUT + c] = 0.0f; return; }
    const float* xr = x + (size_t)r * K_DIM;
    const float* wr = W + (size_t)c * K_DIM;
    float s = 0.0f;
    for (int k = 0; k < K_DIM; ++k) s += xr[k] * wr[k];
    out[(size_t)r * N_OUT + c] = s + bias[c];
}

extern "C" void kernel_launch(void* const* d_in, const int* in_sizes, int n_in,
                              void* d_out, int out_size, void* d_ws, size_t ws_size,
                              hipStream_t stream) {
    const float* x     = (const float*)d_in[0];
    const int*   amask = (const int*)d_in[1];
    const float* W     = (const float*)d_in[2];
    const float* bias  = (const float*)d_in[3];
    float*       out   = (float*)d_out;

    const size_t xb_bytes = (size_t)N_ROWS * K_DIM * 2;   // 32 MB
    const size_t wb_bytes = (size_t)N_OUT  * K_DIM * 2;   //  8 MB
    const size_t idx_bytes = (size_t)N_ROWS * 4;          // 64 KB
    const size_t need = xb_bytes + wb_bytes + 2 * idx_bytes + 256;

    if (ws_size < need) {
        dim3 g((N_OUT + 255) / 256, N_ROWS);
        naive_kernel<<<g, 256, 0, stream>>>(x, W, bias, amask, out);
        return;
    }

    __bf16* xb   = (__bf16*)d_ws;
    __bf16* wb   = (__bf16*)((char*)d_ws + xb_bytes);
    int*    idx  = (int*)((char*)d_ws + xb_bytes + wb_bytes);
    int*    zidx = idx + N_ROWS;
    int*    cnt  = zidx + N_ROWS;

    prep_kernel<<<1025, 1024, 0, stream>>>(amask, W, idx, zidx, cnt, wb);
    gather_kernel<<<2048, 256, 0, stream>>>(x, idx, cnt, xb);
    gemm_kernel<<<4096, 256, 0, stream>>>(xb, wb, bias, idx, zidx, cnt, out);
}